// Round 7
// baseline (543.563 us; speedup 1.0000x reference)
//
#include <hip/hip_runtime.h>
#include <stdint.h>
#include <string.h>

#define BB 256
#define TT 2048
#define DD 64
#define C_L2E 1.44269504f
#define C_LN2 0.69314718f
// log2(1 + 2^-9): compensates bf16 truncation bias of the pack, folded into staging exp
#define C_BIAS 0.0028174f

typedef short sh8  __attribute__((ext_vector_type(8)));
typedef float f32x4 __attribute__((ext_vector_type(4)));

__device__ __forceinline__ float expf_fast(float x) { return __builtin_amdgcn_exp2f(x * C_L2E); }
__device__ __forceinline__ unsigned short bf16rne(float x) {
    unsigned int u = __float_as_uint(x);
    u += 0x7FFF + ((u >> 16) & 1u);
    return (unsigned short)(u >> 16);
}

#define DPPMAX(x, ctrl, rm, bm) { int _xi = __float_as_int(x);                              \
    int _yi = __builtin_amdgcn_update_dpp(_xi, _xi, ctrl, rm, bm, false);                   \
    x = fmaxf(x, __int_as_float(_yi)); }

// ---------- kernel 1: scores via wave-ballot labels; one wave per timestep ----------
__global__ __launch_bounds__(256) void crf_score(
    const float* __restrict__ p, const int* __restrict__ y,
    const int* __restrict__ mask, const float* __restrict__ tr,
    float* __restrict__ wsS)
{
    __shared__ unsigned char labs[65];
    __shared__ float redf[4];
    const int c = blockIdx.y, t0 = blockIdx.x * 64;
    const int tid = threadIdx.x, w = tid >> 6, l = tid & 63;
    const size_t cb = (size_t)c * TT;

    float s1 = 0.f;
#pragma unroll
    for (int i = 0; i < 16; ++i) {
        int t = t0 + i * 4 + w;
        if (mask[cb + t] == 0) {
            int yv = y[(cb + t) * DD + l];                 // coalesced 256 B / wave
            unsigned long long bal = __ballot(yv != 0);
            int lab = (int)__builtin_ctzll(bal);
            if (l == 0) labs[i * 4 + w] = (unsigned char)lab;
            if (yv != 0) s1 += p[(cb + t) * DD + l];       // single-lane masked gather
        }
    }
    if (w == 0) {                                          // boundary label t0+64
        int t = t0 + 64;
        if (t < TT && mask[cb + t] == 0) {
            int yv = y[(cb + t) * DD + l];
            unsigned long long bal = __ballot(yv != 0);
            if (l == 0) labs[64] = (unsigned char)__builtin_ctzll(bal);
        }
    }
    __syncthreads();
    float s2 = 0.f;
    if (tid < 64) {
        int t = t0 + tid;
        if (t + 1 < TT && mask[cb + t + 1] == 0)           // pair valid (prefix property)
            s2 = tr[(int)labs[tid] * DD + (int)labs[tid + 1]];
    }
    float acc = s1 + s2;
#pragma unroll
    for (int xm = 32; xm >= 1; xm >>= 1) acc += __shfl_xor(acc, xm, 64);
    if (l == 0) redf[w] = acc;
    __syncthreads();
    if (tid == 0) atomicAdd(&wsS[c], redf[0] + redf[1] + redf[2] + redf[3]);
}

// ---------- kernel 2: chunk transfer matrices H = prod_t diag(e_t) W^T  (bf16 MFMA) ----------
// 4 waves per block; wave w owns 16 columns [16w, 16w+16). Per step per wave: 8 MFMA.
// Contraction relabeling lam(kt2,j,q) = 32kt2 + 16(j>>2) + 4q + (j&3) keeps D->B in-lane.
union BU { sh8 v8; unsigned int u[4]; unsigned short s[8]; };

__global__ __launch_bounds__(256, 4) void crf_chunk(
    const float* __restrict__ p, const float* __restrict__ tr,
    const int* __restrict__ mask,
    unsigned short* __restrict__ wsH, int* __restrict__ wsK,
    int C, int S)
{
    __shared__ float E[64 * 64];      // 16 KB: 64-step staging window
    __shared__ int cntw[4];
    const int c = blockIdx.x, ic = blockIdx.y;
    const int t0 = ic * S;
    const int tid = threadIdx.x, w = tid >> 6, lane = tid & 63;
    const int q = lane >> 4, ml = lane & 15;
    const int col = 16 * w + ml;

    // local valid count in [t0, t0+S) (validity is a prefix)
    int cnt = 0;
    for (int tt = tid; tt < S; tt += 256) {
        int mv = mask[(size_t)c * TT + t0 + tt];
        cnt += __popcll(__ballot(mv == 0));
    }
    if (lane == 0) cntw[w] = cnt;

    // A = W^T resident: A[mt][kt2].s[j] = bf16(exp(T[lam][16mt+ml]))
    BU A[4][2];
#pragma unroll
    for (int mt = 0; mt < 4; ++mt)
#pragma unroll
        for (int kt2 = 0; kt2 < 2; ++kt2)
#pragma unroll
            for (int j = 0; j < 8; ++j) {
                int lam = 32 * kt2 + 16 * (j >> 2) + 4 * q + (j & 3);
                A[mt][kt2].s[j] = (short)bf16rne(expf_fast(tr[lam * DD + 16 * mt + ml]));
            }

    // B init = identity (cols of this wave)
    BU Bf[2];
#pragma unroll
    for (int kt2 = 0; kt2 < 2; ++kt2)
#pragma unroll
        for (int j = 0; j < 8; ++j) {
            int lam = 32 * kt2 + 16 * (j >> 2) + 4 * q + (j & 3);
            Bf[kt2].s[j] = (short)((lam == col) ? 0x3F80 : 0);
        }

    __syncthreads();
    const int te = t0 + cntw[0] + cntw[1] + cntw[2] + cntw[3];

    int sig = 0;
    const f32x4 z4 = {0.f, 0.f, 0.f, 0.f};

    for (int base = t0; base < te; base += 64) {
        __syncthreads();
        {   // stage E = exp(p)*(1+2^-9) for [base, base+64) as f32
            const f32x4* p4 = (const f32x4*)(p + ((size_t)c * TT + base) * DD);
#pragma unroll
            for (int k2 = 0; k2 < 4; ++k2) {
                int idx = k2 * 256 + tid;
                f32x4 v = p4[idx];
                f32x4 ex;
                ex[0] = __builtin_amdgcn_exp2f(fmaf(v[0], C_L2E, C_BIAS));
                ex[1] = __builtin_amdgcn_exp2f(fmaf(v[1], C_L2E, C_BIAS));
                ex[2] = __builtin_amdgcn_exp2f(fmaf(v[2], C_L2E, C_BIAS));
                ex[3] = __builtin_amdgcn_exp2f(fmaf(v[3], C_L2E, C_BIAS));
                *((f32x4*)E + idx) = ex;
            }
        }
        __syncthreads();
        const int tend = (base + 64 < te) ? base + 64 : te;
        const int ts = (base == 0) ? 1 : base;      // t=0 folded into combine's u_0

        f32x4 er[4];
#pragma unroll
        for (int mt = 0; mt < 4; ++mt)
            er[mt] = *(const f32x4*)(E + (ts - base) * 64 + 16 * mt + 4 * q);

        for (int t = ts; t < tend; ++t) {
            f32x4 acc[4];
#pragma unroll
            for (int mt = 0; mt < 4; ++mt) {
                acc[mt] = __builtin_amdgcn_mfma_f32_16x16x32_bf16(A[mt][0].v8, Bf[0].v8, z4, 0, 0, 0);
                acc[mt] = __builtin_amdgcn_mfma_f32_16x16x32_bf16(A[mt][1].v8, Bf[1].v8, acc[mt], 0, 0, 0);
            }
            // prefetch next step's e-rows while MFMA is in flight
            f32x4 ern[4];
            const bool more = (t + 1 < tend);
            if (more) {
#pragma unroll
                for (int mt = 0; mt < 4; ++mt)
                    ern[mt] = *(const f32x4*)(E + (t + 1 - base) * 64 + 16 * mt + 4 * q);
            }
            if ((t & 7) == 7) {   // renorm every 8th step (power of 2, exact bookkeeping)
                float mx = fabsf(acc[0][0]);
#pragma unroll
                for (int mt = 1; mt < 4; ++mt) mx = fmaxf(mx, fabsf(acc[mt][0]));
                DPPMAX(mx, 0x111, 0xF, 0xF); DPPMAX(mx, 0x112, 0xF, 0xF);
                DPPMAX(mx, 0x114, 0xF, 0xF); DPPMAX(mx, 0x118, 0xF, 0xF);
                DPPMAX(mx, 0x142, 0xA, 0xF); DPPMAX(mx, 0x143, 0xC, 0xF);
                int smx = __builtin_amdgcn_readlane(__float_as_int(mx), 63);
                int kk = ((smx >> 23) & 255) - 127 + 6;   // scale sampled max to ~2^-6
                kk = kk < -124 ? -124 : (kk > 124 ? 124 : kk);
                sig += kk;
                float sc = __int_as_float((unsigned)(127 - kk) << 23);
#pragma unroll
                for (int mt = 0; mt < 4; ++mt) {
                    er[mt][0] *= sc; er[mt][1] *= sc; er[mt][2] *= sc; er[mt][3] *= sc;
                }
            }
            // pack D -> next B with row-scale e (in-lane, lam order)
#pragma unroll
            for (int kt2 = 0; kt2 < 2; ++kt2)
#pragma unroll
                for (int r = 0; r < 4; ++r) {
                    int mt = 2 * kt2 + (r >> 1);
                    int e0 = 2 * (r & 1);
                    float x0 = acc[mt][e0]     * er[mt][e0];
                    float x1 = acc[mt][e0 + 1] * er[mt][e0 + 1];
                    Bf[kt2].u[r] = __builtin_amdgcn_perm(__float_as_uint(x1), __float_as_uint(x0), 0x07060302u);
                }
            if (more) {
#pragma unroll
                for (int mt = 0; mt < 4; ++mt) er[mt] = ern[mt];
            }
        }
    }

    // store H (row-major [64][64] bf16) + per-column-quarter log2 scale
    unsigned short* Hd = wsH + ((size_t)(c * C + ic)) * 4096;
#pragma unroll
    for (int kt2 = 0; kt2 < 2; ++kt2)
#pragma unroll
        for (int j = 0; j < 8; ++j) {
            int lam = 32 * kt2 + 16 * (j >> 2) + 4 * q + (j & 3);
            Hd[lam * 64 + col] = (unsigned short)Bf[kt2].s[j];
        }
    if (lane == 0) wsK[(c * C + ic) * 4 + w] = sig;
}

// ---------- kernel 3: per-chain combine (prefetched) + logZ - score ----------
__global__ __launch_bounds__(256) void crf_combine(
    const float* __restrict__ p, const unsigned short* __restrict__ wsH,
    const int* __restrict__ wsK, const float* __restrict__ wsS,
    float* __restrict__ out, int C)
{
    __shared__ float U[4][64];
    const int tid = threadIdx.x, w = tid >> 6, lane = tid & 63;
    const int c = blockIdx.x * 4 + w;

    U[w][lane] = expf_fast(p[(size_t)c * TT * DD + lane]);   // u_0 = exp(p_0)
    int Esc = 0;
    float o = 0.f;

    uint4 h[8];
    {
        const uint4* hp = (const uint4*)(wsH + ((size_t)(c * C)) * 4096) + lane * 8;
#pragma unroll
        for (int i = 0; i < 8; ++i) h[i] = hp[i];
    }
    for (int ic = 0; ic < C; ++ic) {
        uint4 hn[8];
        if (ic + 1 < C) {
            const uint4* hp = (const uint4*)(wsH + ((size_t)(c * C + ic + 1)) * 4096) + lane * 8;
#pragma unroll
            for (int i = 0; i < 8; ++i) hn[i] = hp[i];
        }
        float aq[4] = {0.f, 0.f, 0.f, 0.f};
#pragma unroll
        for (int i = 0; i < 8; ++i) {
            unsigned int uu[4] = {h[i].x, h[i].y, h[i].z, h[i].w};
#pragma unroll
            for (int k = 0; k < 4; ++k) {
                int cidx = i * 8 + k * 2;
                float h0 = __uint_as_float(uu[k] << 16);
                float h1 = __uint_as_float(uu[k] & 0xFFFF0000u);
                aq[i >> 1] = fmaf(h0, U[w][cidx], aq[i >> 1]);
                aq[i >> 1] = fmaf(h1, U[w][cidx + 1], aq[i >> 1]);
            }
        }
        int s[4];
#pragma unroll
        for (int k = 0; k < 4; ++k) s[k] = wsK[(c * C + ic) * 4 + k];
        int m = s[0];
#pragma unroll
        for (int k = 1; k < 4; ++k) m = s[k] > m ? s[k] : m;
        o = ldexpf(aq[0], s[0] - m) + ldexpf(aq[1], s[1] - m)
          + ldexpf(aq[2], s[2] - m) + ldexpf(aq[3], s[3] - m);
        Esc += m;
        float mo = o;
#pragma unroll
        for (int xm = 32; xm >= 1; xm >>= 1) mo = fmaxf(mo, __shfl_xor(mo, xm, 64));
        int k2 = ((__float_as_int(mo) >> 23) & 255) - 127;
        k2 = k2 < -120 ? -120 : (k2 > 120 ? 120 : k2);
        Esc += k2;
        o = ldexpf(o, -k2);
        U[w][lane] = o;
#pragma unroll
        for (int i = 0; i < 8; ++i) h[i] = hn[i];
    }
    float sum = o;
#pragma unroll
    for (int xm = 32; xm >= 1; xm >>= 1) sum += __shfl_xor(sum, xm, 64);
    float logZ = C_LN2 * (__builtin_amdgcn_logf(sum) + (float)Esc);
    if (lane == 0) out[c] = logZ - wsS[c];
}

extern "C" void kernel_launch(void* const* d_in, const int* in_sizes, int n_in,
                              void* d_out, int out_size, void* d_ws, size_t ws_size,
                              hipStream_t stream) {
    const float* p  = (const float*)d_in[0];
    const int*   y  = (const int*)d_in[1];
    const int*   mk = (const int*)d_in[2];
    const float* tr = (const float*)d_in[3];
    float* out = (float*)d_out;

    float* wsS = (float*)d_ws;                               // 1 KB
    int*   wsK = (int*)((char*)d_ws + 1024);                 // 64 KB
    unsigned short* wsH = (unsigned short*)((char*)d_ws + 66560);

    int C = 16;
    if (ws_size < 66560 + (size_t)BB * 16 * 4096 * 2) C = 8;
    if (ws_size < 66560 + (size_t)BB * 8 * 4096 * 2)  C = 4;
    int S = TT / C;

    hipMemsetAsync(wsS, 0, BB * sizeof(float), stream);
    crf_score<<<dim3(TT / 64, BB), dim3(256), 0, stream>>>(p, y, mk, tr, wsS);
    crf_chunk<<<dim3(BB, C), dim3(256), 0, stream>>>(p, tr, mk, wsH, wsK, C, S);
    crf_combine<<<dim3(BB / 4), dim3(256), 0, stream>>>(p, wsH, wsK, wsS, out, C);
}

// Round 8
// 336.820 us; speedup vs baseline: 1.6138x; 1.6138x over previous
//
#include <hip/hip_runtime.h>
#include <stdint.h>
#include <string.h>

#define BB 256
#define TT 2048
#define DD 64
#define C_L2E 1.44269504f
#define C_LN2 0.69314718f
// log2(1 + 2^-9): compensates bf16 truncation bias of the pack, folded into exp
#define C_BIAS 0.0028174f

typedef short sh8  __attribute__((ext_vector_type(8)));
typedef float f32x4 __attribute__((ext_vector_type(4)));

union BU { sh8 v8; unsigned int u[4]; unsigned short s[8]; };

__device__ __forceinline__ float expf_fast(float x) { return __builtin_amdgcn_exp2f(x * C_L2E); }
__device__ __forceinline__ unsigned short bf16rne(float x) {
    unsigned int u = __float_as_uint(x);
    u += 0x7FFF + ((u >> 16) & 1u);
    return (unsigned short)(u >> 16);
}
__device__ __forceinline__ unsigned int pkbf(float hi, float lo) {
    return __builtin_amdgcn_perm(__float_as_uint(hi), __float_as_uint(lo), 0x07060302u);
}

#define DPPMAX(x, ctrl, rm, bm) { int _xi = __float_as_int(x);                              \
    int _yi = __builtin_amdgcn_update_dpp(_xi, _xi, ctrl, rm, bm, false);                   \
    x = fmaxf(x, __int_as_float(_yi)); }

// ---------- kernel 1: scores + lengths (parallel over (c, 256-token blocks)) ----------
__global__ __launch_bounds__(256) void crf_score(
    const float* __restrict__ p, const int* __restrict__ y,
    const int* __restrict__ mask, const float* __restrict__ tr,
    float* __restrict__ wsS, int* __restrict__ wsL)
{
    __shared__ unsigned char labs[257];
    __shared__ float redf[4];
    __shared__ int redi[4];
    const int c = blockIdx.y, t0 = blockIdx.x * 256;
    const int tid = threadIdx.x;
    const int t = t0 + tid;

    const int mv = mask[(size_t)c * TT + t];
    float s1 = 0.f, s2 = 0.f;
    int vc = (mv == 0) ? 1 : 0;
    if (mv == 0) {
        const int4* yt = (const int4*)y + ((size_t)c * TT + t) * 16;
        int lab = 0;
#pragma unroll
        for (int g = 0; g < 16; ++g) {
            int4 v = yt[g];
            if (v.x) lab = 4 * g;     if (v.y) lab = 4 * g + 1;
            if (v.z) lab = 4 * g + 2; if (v.w) lab = 4 * g + 3;
        }
        labs[tid] = (unsigned char)lab;
        s1 = p[((size_t)c * TT + t) * DD + lab];
    }
    if (tid == 0) {
        int tb = t0 + 256;
        if (tb < TT && mask[(size_t)c * TT + tb] == 0) {
            const int4* yt = (const int4*)y + ((size_t)c * TT + tb) * 16;
            int lab = 0;
#pragma unroll
            for (int g = 0; g < 16; ++g) {
                int4 v = yt[g];
                if (v.x) lab = 4 * g;     if (v.y) lab = 4 * g + 1;
                if (v.z) lab = 4 * g + 2; if (v.w) lab = 4 * g + 3;
            }
            labs[256] = (unsigned char)lab;
        }
    }
    __syncthreads();
    if (t + 1 < TT && mask[(size_t)c * TT + t + 1] == 0)   // pair valid (prefix property)
        s2 = tr[(int)labs[tid] * DD + (int)labs[tid + 1]];

    float acc = s1 + s2;
#pragma unroll
    for (int xm = 32; xm >= 1; xm >>= 1) { acc += __shfl_xor(acc, xm, 64); vc += __shfl_xor(vc, xm, 64); }
    if ((tid & 63) == 0) { redf[tid >> 6] = acc; redi[tid >> 6] = vc; }
    __syncthreads();
    if (tid == 0) {
        atomicAdd(&wsS[c], redf[0] + redf[1] + redf[2] + redf[3]);
        atomicAdd(&wsL[c], redi[0] + redi[1] + redi[2] + redi[3]);
    }
}

// ---------- kernel 2: rank-1 chunk probes (fwd: a = H q ; bwd: b = H^T 1) ----------
// Wave batches 16 chains (c = 16cg+ml), one chunk ic, one direction. Per step: 8 MFMA
// 16x16x32 bf16. State in f32[16] per lane, lambda-relabelled (lam = 32kt2+16h+4q+r)
// so D -> next-B is in-lane. e = exp(p) gathered per-lane (dwordx4, coalesced 64B/chain),
// prefetched 4 steps. Wave-uniform pow-2 renorm every 4 steps, per-chain sig; padding
// steps handled by per-chain freeze-select (M_t = I).
__global__ __launch_bounds__(256) void crf_probe(
    const float* __restrict__ p, const float* __restrict__ tr,
    const int* __restrict__ wsL,
    float* __restrict__ wsA, float* __restrict__ wsB, int* __restrict__ wsSig)
{
    const int tid = threadIdx.x, w = tid >> 6, lane = tid & 63;
    const int q = lane >> 4, ml = lane & 15;
    const int cg = blockIdx.x;
    const int ic = blockIdx.y * 4 + w;
    const int bwd = blockIdx.z;
    const int c = cg * 16 + ml;
    const int Lml = wsL[c];
    const int t0 = ic * 128, t1 = t0 + 128;
    const int ts = (ic == 0) ? 1 : t0;
    const float* prow = p + (size_t)c * TT * DD;

    // A fragments: fwd A = W^T (exp(T[lam][row])), bwd A = W (exp(T[row][lam]))
    BU A[4][2];
#pragma unroll
    for (int mt = 0; mt < 4; ++mt)
#pragma unroll
        for (int kt2 = 0; kt2 < 2; ++kt2)
#pragma unroll
            for (int j = 0; j < 8; ++j) {
                int lam = 32 * kt2 + 16 * (j >> 2) + 4 * q + (j & 3);
                float tv = bwd ? tr[(16 * mt + ml) * DD + lam] : tr[lam * DD + 16 * mt + ml];
                A[mt][kt2].s[j] = (short)bf16rne(expf_fast(tv));
            }

    // state xs[idx], idx = kt2*8 + h*4 + r  <->  lam = 32kt2+16h+4q+r
    float xs[16];
    if (!bwd && ic == 0) {           // exact start: u0 = exp(p[c,0,:])
#pragma unroll
        for (int k = 0; k < 4; ++k) {
            f32x4 v = *(const f32x4*)(prow + 16 * k + 4 * q);
#pragma unroll
            for (int r = 0; r < 4; ++r)
                xs[(k >> 1) * 8 + (k & 1) * 4 + r] = __builtin_amdgcn_exp2f(fmaf(v[r], C_L2E, C_BIAS));
        }
    } else {
#pragma unroll
        for (int i = 0; i < 16; ++i) xs[i] = 1.0f;
    }

    // wave max of L -> skip all-frozen step ranges
    int mL = Lml;
#pragma unroll
    for (int xm = 32; xm >= 1; xm >>= 1) { int o = __shfl_xor(mL, xm, 64); mL = o > mL ? o : mL; }
    int ibeg = 0, iend = 128;
    if (!bwd) { int ir = mL - t0; if (ir < 0) ir = 0; iend = (ir + 3) & ~3; if (iend > 128) iend = 128; }
    else      { int ir = t1 - mL; if (ir < 0) ir = 0; ibeg = ir & ~3; if (ibeg > 128) ibeg = 128; }

    int sig = 0;
    const f32x4 z4 = {0.f, 0.f, 0.f, 0.f};

    if (ibeg < iend) {
        f32x4 er[4][4];
#pragma unroll
        for (int s = 0; s < 4; ++s) {
            int i = ibeg + s;
            int t = bwd ? (t1 - 1 - i) : (t0 + i);
#pragma unroll
            for (int k = 0; k < 4; ++k)
                er[s][k] = *(const f32x4*)(prow + (size_t)t * DD + 16 * k + 4 * q);
        }
        for (int ib = ibeg; ib < iend; ib += 4) {
#pragma unroll
            for (int s = 0; s < 4; ++s) {
                const int i = ib + s;
                const int t = bwd ? (t1 - 1 - i) : (t0 + i);
                const bool act = (t >= ts) && (t < Lml);
                float ee[4][4];
#pragma unroll
                for (int k = 0; k < 4; ++k)
#pragma unroll
                    for (int r = 0; r < 4; ++r)
                        ee[k][r] = __builtin_amdgcn_exp2f(fmaf(er[s][k][r], C_L2E, C_BIAS));
                {   // prefetch step i+4 into slot s
                    int ipf = i + 4;
                    int tpf = bwd ? (t1 - 1 - ipf) : (t0 + ipf);
                    if (tpf < t0) tpf = t0;
                    if (tpf > t1 - 1) tpf = t1 - 1;
#pragma unroll
                    for (int k = 0; k < 4; ++k)
                        er[s][k] = *(const f32x4*)(prow + (size_t)tpf * DD + 16 * k + 4 * q);
                }
                float cand[16];
                BU Bf[2];
                f32x4 acc[4];
                if (!bwd) {     // u' = diag(e) W^T u : scale on output
#pragma unroll
                    for (int kt2 = 0; kt2 < 2; ++kt2)
#pragma unroll
                        for (int jj = 0; jj < 4; ++jj)
                            Bf[kt2].u[jj] = pkbf(xs[kt2 * 8 + 2 * jj + 1], xs[kt2 * 8 + 2 * jj]);
#pragma unroll
                    for (int mt = 0; mt < 4; ++mt) {
                        acc[mt] = __builtin_amdgcn_mfma_f32_16x16x32_bf16(A[mt][0].v8, Bf[0].v8, z4, 0, 0, 0);
                        acc[mt] = __builtin_amdgcn_mfma_f32_16x16x32_bf16(A[mt][1].v8, Bf[1].v8, acc[mt], 0, 0, 0);
                    }
#pragma unroll
                    for (int mt = 0; mt < 4; ++mt)
#pragma unroll
                        for (int r = 0; r < 4; ++r)
                            cand[(mt >> 1) * 8 + (mt & 1) * 4 + r] = acc[mt][r] * ee[mt][r];
                } else {        // w' = W (e .* w) : scale on input
                    float xsc[16];
#pragma unroll
                    for (int kt2 = 0; kt2 < 2; ++kt2)
#pragma unroll
                        for (int h = 0; h < 2; ++h)
#pragma unroll
                            for (int r = 0; r < 4; ++r)
                                xsc[kt2 * 8 + h * 4 + r] = xs[kt2 * 8 + h * 4 + r] * ee[2 * kt2 + h][r];
#pragma unroll
                    for (int kt2 = 0; kt2 < 2; ++kt2)
#pragma unroll
                        for (int jj = 0; jj < 4; ++jj)
                            Bf[kt2].u[jj] = pkbf(xsc[kt2 * 8 + 2 * jj + 1], xsc[kt2 * 8 + 2 * jj]);
#pragma unroll
                    for (int mt = 0; mt < 4; ++mt) {
                        acc[mt] = __builtin_amdgcn_mfma_f32_16x16x32_bf16(A[mt][0].v8, Bf[0].v8, z4, 0, 0, 0);
                        acc[mt] = __builtin_amdgcn_mfma_f32_16x16x32_bf16(A[mt][1].v8, Bf[1].v8, acc[mt], 0, 0, 0);
                    }
#pragma unroll
                    for (int mt = 0; mt < 4; ++mt)
#pragma unroll
                        for (int r = 0; r < 4; ++r)
                            cand[(mt >> 1) * 8 + (mt & 1) * 4 + r] = acc[mt][r];
                }
                if (s == 3) {   // wave-uniform pow-2 renorm, per-chain sig
                    float mx = fabsf(cand[0]);
#pragma unroll
                    for (int i2 = 1; i2 < 16; ++i2) mx = fmaxf(mx, fabsf(cand[i2]));
                    DPPMAX(mx, 0x111, 0xF, 0xF); DPPMAX(mx, 0x112, 0xF, 0xF);
                    DPPMAX(mx, 0x114, 0xF, 0xF); DPPMAX(mx, 0x118, 0xF, 0xF);
                    DPPMAX(mx, 0x142, 0xA, 0xF); DPPMAX(mx, 0x143, 0xC, 0xF);
                    int smx = __builtin_amdgcn_readlane(__float_as_int(mx), 63);
                    int kk = ((smx >> 23) & 255) - 127;
                    kk = kk < -124 ? -124 : (kk > 124 ? 124 : kk);
                    float sc = __int_as_float((unsigned)(127 - kk) << 23);
#pragma unroll
                    for (int i2 = 0; i2 < 16; ++i2) cand[i2] *= sc;
                    if (act) sig += kk;
                }
#pragma unroll
                for (int i2 = 0; i2 < 16; ++i2) xs[i2] = act ? cand[i2] : xs[i2];
            }
        }
    }

    float* dst = (bwd ? wsB : wsA) + ((size_t)c * 16 + ic) * 64;
#pragma unroll
    for (int kt2 = 0; kt2 < 2; ++kt2)
#pragma unroll
        for (int h = 0; h < 2; ++h)
#pragma unroll
            for (int r = 0; r < 4; ++r)
                dst[32 * kt2 + 16 * h + 4 * q + r] = xs[kt2 * 8 + h * 4 + r];
    if (!bwd && q == 0) wsSig[c * 16 + ic] = sig;
}

// ---------- kernel 3: scalar rank-1 combine per chain ----------
__global__ __launch_bounds__(256) void crf_combine(
    const float* __restrict__ wsA, const float* __restrict__ wsB,
    const int* __restrict__ wsSig, const float* __restrict__ wsS,
    float* __restrict__ out)
{
    const int tid = threadIdx.x, w = tid >> 6, lane = tid & 63;
    const int c = blockIdx.x * 4 + w;
    float a[16], b[16];
#pragma unroll
    for (int i = 0; i < 16; ++i) {
        a[i] = wsA[((size_t)c * 16 + i) * 64 + lane];
        b[i] = wsB[((size_t)c * 16 + i) * 64 + lane];
    }
    float E = (float)wsSig[c * 16];
    float curl = a[0];
#pragma unroll
    for (int i = 1; i < 16; ++i) {
        float d1 = b[i] * curl;
        float d0 = b[i];
#pragma unroll
        for (int xm = 32; xm >= 1; xm >>= 1) { d1 += __shfl_xor(d1, xm, 64); d0 += __shfl_xor(d0, xm, 64); }
        E += (float)wsSig[c * 16 + i] + __builtin_amdgcn_logf(d1) - __builtin_amdgcn_logf(d0);
        curl = a[i];
    }
    float sum = curl;
#pragma unroll
    for (int xm = 32; xm >= 1; xm >>= 1) sum += __shfl_xor(sum, xm, 64);
    float logZ = C_LN2 * (__builtin_amdgcn_logf(sum) + E);
    if (lane == 0) out[c] = logZ - wsS[c];
}

extern "C" void kernel_launch(void* const* d_in, const int* in_sizes, int n_in,
                              void* d_out, int out_size, void* d_ws, size_t ws_size,
                              hipStream_t stream) {
    const float* p  = (const float*)d_in[0];
    const int*   y  = (const int*)d_in[1];
    const int*   mk = (const int*)d_in[2];
    const float* tr = (const float*)d_in[3];
    float* out = (float*)d_out;

    float* wsS  = (float*)d_ws;                                   // 1 KB
    int*   wsL  = (int*)((char*)d_ws + 1024);                     // 1 KB
    int*   wsSg = (int*)((char*)d_ws + 2048);                     // 16 KB
    float* wsA  = (float*)((char*)d_ws + 32768);                  // 1 MB
    float* wsB  = (float*)((char*)d_ws + 32768 + (1u << 20));     // 1 MB

    hipMemsetAsync(d_ws, 0, 2048, stream);
    crf_score<<<dim3(8, BB), dim3(256), 0, stream>>>(p, y, mk, tr, wsS, wsL);
    crf_probe<<<dim3(16, 4, 2), dim3(256), 0, stream>>>(p, tr, wsL, wsA, wsB, wsSg);
    crf_combine<<<dim3(BB / 4), dim3(256), 0, stream>>>(wsA, wsB, wsSg, wsS, out);
}

// Round 10
// 317.457 us; speedup vs baseline: 1.7122x; 1.0610x over previous
//
#include <hip/hip_runtime.h>
#include <stdint.h>
#include <string.h>

#define BB 256
#define TT 2048
#define DD 64
#define CC 64          // chunks per chain
#define SS 32          // steps per chunk
#define C_L2E 1.44269504f
#define C_LN2 0.69314718f
// log2(1 + 2^-9): compensates bf16 truncation bias of the pack, folded into exp
#define C_BIAS 0.0028174f

typedef short sh8  __attribute__((ext_vector_type(8)));
typedef float f32x4 __attribute__((ext_vector_type(4)));

union BU { sh8 v8; unsigned int u[4]; unsigned short s[8]; };

__device__ __forceinline__ float expf_fast(float x) { return __builtin_amdgcn_exp2f(x * C_L2E); }
__device__ __forceinline__ unsigned short bf16rne(float x) {
    unsigned int u = __float_as_uint(x);
    u += 0x7FFF + ((u >> 16) & 1u);
    return (unsigned short)(u >> 16);
}
__device__ __forceinline__ unsigned int pkbf(float hi, float lo) {
    return __builtin_amdgcn_perm(__float_as_uint(hi), __float_as_uint(lo), 0x07060302u);
}

#define DPPMAX(x, ctrl, rm, bm) { int _xi = __float_as_int(x);                              \
    int _yi = __builtin_amdgcn_update_dpp(_xi, _xi, ctrl, rm, bm, false);                   \
    x = fmaxf(x, __int_as_float(_yi)); }

// ---------- kernel 1: scores + lengths; 16 threads per token, fully coalesced y ----------
__global__ __launch_bounds__(256) void crf_score(
    const float* __restrict__ p, const int* __restrict__ y,
    const int* __restrict__ mask, const float* __restrict__ tr,
    float* __restrict__ wsS, int* __restrict__ wsL)
{
    __shared__ int mk[257];
    __shared__ unsigned char labs[257];
    __shared__ float redf[4];
    __shared__ int redi[4];
    const int c = blockIdx.y, t0 = blockIdx.x * 256;
    const int tid = threadIdx.x;
    const int g = tid & 15, sub = tid >> 4;
    const size_t cb = (size_t)c * TT;

    mk[tid] = mask[cb + t0 + tid];
    if (tid == 0) mk[256] = (t0 + 256 < TT) ? mask[cb + t0 + 256] : 1;
    __syncthreads();

    float s1 = 0.f;
    int vc = 0;
#pragma unroll
    for (int k = 0; k < 16; ++k) {
        const int ti = k * 16 + sub;            // token index within block
        if (mk[ti] == 0) {
            int4 v = ((const int4*)y)[(cb + t0 + ti) * 16 + g];   // 4 KB contiguous per iter
            int cand = v.w ? 4 * g + 3 : v.z ? 4 * g + 2 : v.y ? 4 * g + 1 : v.x ? 4 * g : -1;
#pragma unroll
            for (int xm = 1; xm <= 8; xm <<= 1) {
                int o = __shfl_xor(cand, xm, 16);
                cand = o > cand ? o : cand;
            }
            if (g == 0) {
                labs[ti] = (unsigned char)cand;
                s1 += p[(cb + t0 + ti) * DD + cand];   // ACCUMULATE (R9 bug: was '=')
                vc += 1;                               // ACCUMULATE (R9 bug: was '=1')
            }
        }
    }
    if (tid < 16 && mk[256] == 0) {             // boundary label t0+256
        int4 v = ((const int4*)y)[(cb + t0 + 256) * 16 + tid];
        int cand = v.w ? 4 * tid + 3 : v.z ? 4 * tid + 2 : v.y ? 4 * tid + 1 : v.x ? 4 * tid : -1;
#pragma unroll
        for (int xm = 1; xm <= 8; xm <<= 1) {
            int o = __shfl_xor(cand, xm, 16);
            cand = o > cand ? o : cand;
        }
        if (tid == 0) labs[256] = (unsigned char)cand;
    }
    __syncthreads();

    float s2 = 0.f;
    if (mk[tid + 1] == 0)                       // pair (t,t+1) valid (prefix property)
        s2 = tr[(int)labs[tid] * DD + (int)labs[tid + 1]];

    float acc = s1 + s2;
#pragma unroll
    for (int xm = 32; xm >= 1; xm >>= 1) { acc += __shfl_xor(acc, xm, 64); vc += __shfl_xor(vc, xm, 64); }
    if ((tid & 63) == 0) { redf[tid >> 6] = acc; redi[tid >> 6] = vc; }
    __syncthreads();
    if (tid == 0) {
        atomicAdd(&wsS[c], redf[0] + redf[1] + redf[2] + redf[3]);
        atomicAdd(&wsL[c], redi[0] + redi[1] + redi[2] + redi[3]);
    }
}

// ---------- kernel 2: rank-1 chunk probes (fwd: a = H q ; bwd: b = H^T 1), S=32 ----------
// Block: 4 waves = (ic0,fwd),(ic0,bwd),(ic1,fwd),(ic1,bwd) — same p slab for L2 reuse.
// Wave batches 16 chains (c = 16cg+ml). Per step: 8 MFMA 16x16x32 bf16; state f32[16]/lane,
// lambda-relabelled (lam = 32kt2+16h+4q+r) so D -> next-B is in-lane. Per-chain freeze for
// padding; wave-uniform pow-2 renorm every 4 steps with per-chain sig. Probes stored bf16.
__global__ __launch_bounds__(256) void crf_probe(
    const float* __restrict__ p, const float* __restrict__ tr,
    const int* __restrict__ wsL,
    unsigned short* __restrict__ wsA, unsigned short* __restrict__ wsB, int* __restrict__ wsSig)
{
    const int tid = threadIdx.x, w = tid >> 6, lane = tid & 63;
    const int q = lane >> 4, ml = lane & 15;
    const int cg = blockIdx.x;
    const int ic = blockIdx.y * 2 + (w >> 1);
    const int bwd = w & 1;
    const int c = cg * 16 + ml;
    const int Lml = wsL[c];
    const int t0 = ic * SS, t1 = t0 + SS;
    const int ts = (ic == 0) ? 1 : t0;
    const float* prow = p + (size_t)c * TT * DD;

    // A fragments: fwd A = W^T (exp(T[lam][row])), bwd A = W (exp(T[row][lam]))
    BU A[4][2];
#pragma unroll
    for (int mt = 0; mt < 4; ++mt)
#pragma unroll
        for (int kt2 = 0; kt2 < 2; ++kt2)
#pragma unroll
            for (int j = 0; j < 8; ++j) {
                int lam = 32 * kt2 + 16 * (j >> 2) + 4 * q + (j & 3);
                float tv = bwd ? tr[(16 * mt + ml) * DD + lam] : tr[lam * DD + 16 * mt + ml];
                A[mt][kt2].s[j] = (short)bf16rne(expf_fast(tv));
            }

    // state xs[idx], idx = kt2*8 + h*4 + r  <->  lam = 32kt2+16h+4q+r
    float xs[16];
    if (!bwd && ic == 0) {           // exact start: u0 = exp(p[c,0,:])
#pragma unroll
        for (int k = 0; k < 4; ++k) {
            f32x4 v = *(const f32x4*)(prow + 16 * k + 4 * q);
#pragma unroll
            for (int r = 0; r < 4; ++r)
                xs[(k >> 1) * 8 + (k & 1) * 4 + r] = __builtin_amdgcn_exp2f(fmaf(v[r], C_L2E, C_BIAS));
        }
    } else {
#pragma unroll
        for (int i = 0; i < 16; ++i) xs[i] = 1.0f;
    }

    // wave max of L -> skip all-frozen step ranges
    int mL = Lml;
#pragma unroll
    for (int xm = 32; xm >= 1; xm >>= 1) { int o = __shfl_xor(mL, xm, 64); mL = o > mL ? o : mL; }
    int ibeg = 0, iend = SS;
    if (!bwd) { int ir = mL - t0; if (ir < 0) ir = 0; iend = (ir + 3) & ~3; if (iend > SS) iend = SS; }
    else      { int ir = t1 - mL; if (ir < 0) ir = 0; ibeg = ir & ~3; if (ibeg > SS) ibeg = SS; }

    int sig = 0;
    const f32x4 z4 = {0.f, 0.f, 0.f, 0.f};

    if (ibeg < iend) {
        f32x4 er[4][4];
#pragma unroll
        for (int s = 0; s < 4; ++s) {
            int i = ibeg + s;
            int t = bwd ? (t1 - 1 - i) : (t0 + i);
#pragma unroll
            for (int k = 0; k < 4; ++k)
                er[s][k] = *(const f32x4*)(prow + (size_t)t * DD + 16 * k + 4 * q);
        }
        for (int ib = ibeg; ib < iend; ib += 4) {
#pragma unroll
            for (int s = 0; s < 4; ++s) {
                const int i = ib + s;
                const int t = bwd ? (t1 - 1 - i) : (t0 + i);
                const bool act = (t >= ts) && (t < Lml);
                float ee[4][4];
#pragma unroll
                for (int k = 0; k < 4; ++k)
#pragma unroll
                    for (int r = 0; r < 4; ++r)
                        ee[k][r] = __builtin_amdgcn_exp2f(fmaf(er[s][k][r], C_L2E, C_BIAS));
                {   // prefetch step i+4 into slot s
                    int ipf = i + 4;
                    int tpf = bwd ? (t1 - 1 - ipf) : (t0 + ipf);
                    if (tpf < t0) tpf = t0;
                    if (tpf > t1 - 1) tpf = t1 - 1;
#pragma unroll
                    for (int k = 0; k < 4; ++k)
                        er[s][k] = *(const f32x4*)(prow + (size_t)tpf * DD + 16 * k + 4 * q);
                }
                float cand[16];
                BU Bf[2];
                f32x4 acc[4];
                if (!bwd) {     // u' = diag(e) W^T u : scale on output
#pragma unroll
                    for (int kt2 = 0; kt2 < 2; ++kt2)
#pragma unroll
                        for (int jj = 0; jj < 4; ++jj)
                            Bf[kt2].u[jj] = pkbf(xs[kt2 * 8 + 2 * jj + 1], xs[kt2 * 8 + 2 * jj]);
#pragma unroll
                    for (int mt = 0; mt < 4; ++mt) {
                        acc[mt] = __builtin_amdgcn_mfma_f32_16x16x32_bf16(A[mt][0].v8, Bf[0].v8, z4, 0, 0, 0);
                        acc[mt] = __builtin_amdgcn_mfma_f32_16x16x32_bf16(A[mt][1].v8, Bf[1].v8, acc[mt], 0, 0, 0);
                    }
#pragma unroll
                    for (int mt = 0; mt < 4; ++mt)
#pragma unroll
                        for (int r = 0; r < 4; ++r)
                            cand[(mt >> 1) * 8 + (mt & 1) * 4 + r] = acc[mt][r] * ee[mt][r];
                } else {        // w' = W (e .* w) : scale on input
                    float xsc[16];
#pragma unroll
                    for (int kt2 = 0; kt2 < 2; ++kt2)
#pragma unroll
                        for (int h = 0; h < 2; ++h)
#pragma unroll
                            for (int r = 0; r < 4; ++r)
                                xsc[kt2 * 8 + h * 4 + r] = xs[kt2 * 8 + h * 4 + r] * ee[2 * kt2 + h][r];
#pragma unroll
                    for (int kt2 = 0; kt2 < 2; ++kt2)
#pragma unroll
                        for (int jj = 0; jj < 4; ++jj)
                            Bf[kt2].u[jj] = pkbf(xsc[kt2 * 8 + 2 * jj + 1], xsc[kt2 * 8 + 2 * jj]);
#pragma unroll
                    for (int mt = 0; mt < 4; ++mt) {
                        acc[mt] = __builtin_amdgcn_mfma_f32_16x16x32_bf16(A[mt][0].v8, Bf[0].v8, z4, 0, 0, 0);
                        acc[mt] = __builtin_amdgcn_mfma_f32_16x16x32_bf16(A[mt][1].v8, Bf[1].v8, acc[mt], 0, 0, 0);
                    }
#pragma unroll
                    for (int mt = 0; mt < 4; ++mt)
#pragma unroll
                        for (int r = 0; r < 4; ++r)
                            cand[(mt >> 1) * 8 + (mt & 1) * 4 + r] = acc[mt][r];
                }
                if (s == 3) {   // wave-uniform pow-2 renorm, per-chain sig
                    float mx = fabsf(cand[0]);
#pragma unroll
                    for (int i2 = 1; i2 < 16; ++i2) mx = fmaxf(mx, fabsf(cand[i2]));
                    DPPMAX(mx, 0x111, 0xF, 0xF); DPPMAX(mx, 0x112, 0xF, 0xF);
                    DPPMAX(mx, 0x114, 0xF, 0xF); DPPMAX(mx, 0x118, 0xF, 0xF);
                    DPPMAX(mx, 0x142, 0xA, 0xF); DPPMAX(mx, 0x143, 0xC, 0xF);
                    int smx = __builtin_amdgcn_readlane(__float_as_int(mx), 63);
                    int kk = ((smx >> 23) & 255) - 127;
                    kk = kk < -124 ? -124 : (kk > 124 ? 124 : kk);
                    float sc = __int_as_float((unsigned)(127 - kk) << 23);
#pragma unroll
                    for (int i2 = 0; i2 < 16; ++i2) cand[i2] *= sc;
                    if (act) sig += kk;
                }
#pragma unroll
                for (int i2 = 0; i2 < 16; ++i2) xs[i2] = act ? cand[i2] : xs[i2];
            }
        }
    }

    unsigned short* dst = (bwd ? wsB : wsA) + ((size_t)c * CC + ic) * 64;
#pragma unroll
    for (int kt2 = 0; kt2 < 2; ++kt2)
#pragma unroll
        for (int h = 0; h < 2; ++h)
#pragma unroll
            for (int r = 0; r < 4; ++r)
                dst[32 * kt2 + 16 * h + 4 * q + r] = bf16rne(xs[kt2 * 8 + h * 4 + r]);
    if (!bwd && q == 0) wsSig[c * CC + ic] = sig;
}

// ---------- kernel 3: parallel rank-1 combine, one block per chain ----------
// logZ/ln2 = sig_0 + sum_{i>=1} [sig_i + log2(b_i.a_{i-1}) - log2(b_i.1)] + log2(1.a_{C-1})
__global__ __launch_bounds__(256) void crf_combine(
    const unsigned short* __restrict__ wsA, const unsigned short* __restrict__ wsB,
    const int* __restrict__ wsSig, const float* __restrict__ wsS,
    float* __restrict__ out)
{
    __shared__ float eParts[4];
    const int tid = threadIdx.x, w = tid >> 6, lane = tid & 63;
    const int c = blockIdx.x;

    float Ep = 0.f;
#pragma unroll
    for (int k = 0; k < 16; ++k) {
        const int i = w * 16 + k;
        if (i == 0) continue;
        float b  = __uint_as_float((unsigned)wsB[((size_t)c * CC + i) * 64 + lane] << 16);
        float ap = __uint_as_float((unsigned)wsA[((size_t)c * CC + i - 1) * 64 + lane] << 16);
        float d1 = b * ap, d0 = b;
#pragma unroll
        for (int xm = 32; xm >= 1; xm >>= 1) { d1 += __shfl_xor(d1, xm, 64); d0 += __shfl_xor(d0, xm, 64); }
        Ep += (float)wsSig[c * CC + i] + __builtin_amdgcn_logf(d1) - __builtin_amdgcn_logf(d0);
    }
    if (w == 0) Ep += (float)wsSig[c * CC];
    if (w == 3) {
        float al = __uint_as_float((unsigned)wsA[((size_t)c * CC + CC - 1) * 64 + lane] << 16);
#pragma unroll
        for (int xm = 32; xm >= 1; xm >>= 1) al += __shfl_xor(al, xm, 64);
        Ep += __builtin_amdgcn_logf(al);
    }
    if (lane == 0) eParts[w] = Ep;
    __syncthreads();
    if (tid == 0) {
        float E = eParts[0] + eParts[1] + eParts[2] + eParts[3];
        out[c] = C_LN2 * E - wsS[c];
    }
}

extern "C" void kernel_launch(void* const* d_in, const int* in_sizes, int n_in,
                              void* d_out, int out_size, void* d_ws, size_t ws_size,
                              hipStream_t stream) {
    const float* p  = (const float*)d_in[0];
    const int*   y  = (const int*)d_in[1];
    const int*   mk = (const int*)d_in[2];
    const float* tr = (const float*)d_in[3];
    float* out = (float*)d_out;

    float* wsS  = (float*)d_ws;                                          // 1 KB
    int*   wsL  = (int*)((char*)d_ws + 1024);                            // 1 KB
    int*   wsSg = (int*)((char*)d_ws + 2048);                            // 64 KB
    unsigned short* wsA = (unsigned short*)((char*)d_ws + 131072);       // 2 MB (bf16)
    unsigned short* wsB = (unsigned short*)((char*)d_ws + 131072 + (2u << 20));  // 2 MB

    hipMemsetAsync(d_ws, 0, 2048, stream);
    crf_score<<<dim3(8, BB), dim3(256), 0, stream>>>(p, y, mk, tr, wsS, wsL);
    crf_probe<<<dim3(16, CC / 2), dim3(256), 0, stream>>>(p, tr, wsL, wsA, wsB, wsSg);
    crf_combine<<<dim3(BB), dim3(256), 0, stream>>>(wsA, wsB, wsSg, wsS, out);
}